// Round 6
// baseline (652.889 us; speedup 1.0000x reference)
//
#include <hip/hip_runtime.h>
#include <stdint.h>

typedef float f2 __attribute__((ext_vector_type(2)));
typedef float f4 __attribute__((ext_vector_type(4)));

// res[l] = floor(16 * b^l), b = exp((ln512 - ln16)/15) in fp32.
__constant__ float c_res[16] = {16.f, 20.f, 25.f, 32.f, 40.f, 50.f, 64.f, 80.f,
                                101.f, 128.f, 161.f, 203.f, 256.f, 322.f, 406.f, 512.f};

#define HASH_MASK ((1u << 19) - 1u)
#define P1 2654435761u
#define P2 805459861u
#define PTS_PER_THREAD 4

// Encode (measured 442us, R4/R5): XCD-pinned tables (blockIdx%8 == level%8),
// x-paired 16B gathers, level-major tmp[l][p] writes (lane-coalesced,
// single-writer full lines -> WRITE 135MB). Encode sits near the per-CU
// outstanding-miss wall (~0.37 tx/cy/CU); unchanged this round.
//
// Epilogue history: R4 no-LDS + NT stores = 437us (NT bypasses L2 write-merge
// -> partial-line RMW at MC). R5 LDS + plain stores = 182us (LDS caps
// occupancy at 4 blocks/CU + barrier + bank conflicts). R6: no-LDS + PLAIN
// stores -- row-major tmp reads already hand each thread its whole point;
// per-thread 128B contiguous plain stores are full-line-merged in L2.
template <bool WRITE_TMP>
__global__ __launch_bounds__(256, 4) void hash_encode_kernel(
    const float* __restrict__ x,
    const float* __restrict__ tables,
    f2* __restrict__ tmp,            // [nl][n_points] level-major
    float* __restrict__ out,         // only used when !WRITE_TMP
    float* __restrict__ mask_out,
    int n_points,
    int blocks_per_phase,
    int level_base_arg,              // used when !two_phase
    int two_phase)                   // 1: grid covers both phases
{
    int bid = blockIdx.x;
    int level_base = level_base_arg;
    if (two_phase) {
        level_base = 0;
        if (bid >= blocks_per_phase) { bid -= blocks_per_phase; level_base = 8; }
    }
    int level = (bid & 7) + level_base;
    // tmp row index: full mode stores all 16 levels; half mode stores 8.
    int trow = two_phase ? level : (bid & 7);
    int chunk = bid >> 3;

    float res  = c_res[level];
    float grid = 1.0f / res;
    const f2* __restrict__ tab =
        (const f2*)tables + ((size_t)level << 19);   // 2^19 float2 per level
    const f4* __restrict__ tab4 = (const f4*)tab;    // 2^18 float4 per level

    int pbase = chunk * (256 * PTS_PER_THREAD) + threadIdx.x;

    uint32_t idx[PTS_PER_THREAD][8];
    float wx[PTS_PER_THREAD], wy[PTS_PER_THREAD], wz[PTS_PER_THREAD];
    bool valid[PTS_PER_THREAD];
    bool bxodd[PTS_PER_THREAD];
    int pp[PTS_PER_THREAD];

    #pragma unroll
    for (int s = 0; s < PTS_PER_THREAD; ++s) {
        int p = pbase + s * 256;
        pp[s] = p;
        valid[s] = (p < n_points);
        int pc = valid[s] ? p : 0;

        // Plain loads: x is re-read once per level (16x); let L2/L3 cache it.
        float x0 = x[3 * (size_t)pc + 0];
        float x1 = x[3 * (size_t)pc + 1];
        float x2 = x[3 * (size_t)pc + 2];

        if (level == 0 && valid[s]) {
            bool keep = (x0 >= 0.f) & (x0 <= 1.f) &
                        (x1 >= 0.f) & (x1 <= 1.f) &
                        (x2 >= 0.f) & (x2 <= 1.f);
            mask_out[pc] = keep ? 1.0f : 0.0f;
        }

        x0 = fminf(fmaxf(x0, 0.f), 1.f);
        x1 = fminf(fmaxf(x1, 0.f), 1.f);
        x2 = fminf(fmaxf(x2, 0.f), 1.f);

        // Keep the exact fp32 sequence of the verified kernel (floor(x/grid)),
        // grid = 1/res: changing to x*res can flip buckets by 1 ulp.
        float b0 = floorf(x0 / grid);
        float b1 = floorf(x1 / grid);
        float b2 = floorf(x2 / grid);

        wx[s] = (x0 - b0 * grid) / grid;
        wy[s] = (x1 - b1 * grid) / grid;
        wz[s] = (x2 - b2 * grid) / grid;

        uint32_t bx = (uint32_t)b0;
        uint32_t by = (uint32_t)b1;
        uint32_t bz = (uint32_t)b2;

        bxodd[s] = (bx & 1u) != 0u;

        uint32_t hx0 = bx;        uint32_t hx1 = bx + 1u;
        uint32_t hy0 = by * P1;   uint32_t hy1 = hy0 + P1;
        uint32_t hz0 = bz * P2;   uint32_t hz1 = hz0 + P2;

        idx[s][0] = (hx0 ^ hy0 ^ hz0) & HASH_MASK;
        idx[s][1] = (hx0 ^ hy0 ^ hz1) & HASH_MASK;
        idx[s][2] = (hx0 ^ hy1 ^ hz0) & HASH_MASK;
        idx[s][3] = (hx0 ^ hy1 ^ hz1) & HASH_MASK;
        idx[s][4] = (hx1 ^ hy0 ^ hz0) & HASH_MASK;
        idx[s][5] = (hx1 ^ hy0 ^ hz1) & HASH_MASK;
        idx[s][6] = (hx1 ^ hy1 ^ hz0) & HASH_MASK;
        idx[s][7] = (hx1 ^ hy1 ^ hz1) & HASH_MASK;
    }

    // Issue all gathers before any consumption. Even-bx lanes: 4x16B paired
    // loads (idx[j] and idx[j]^1 == idx[j+4] share a float4). Odd-bx: 8x8B.
    f2 e[PTS_PER_THREAD][8];
    #pragma unroll
    for (int s = 0; s < PTS_PER_THREAD; ++s) {
        if (!bxodd[s]) {
            #pragma unroll
            for (int j = 0; j < 4; ++j) {
                uint32_t q = idx[s][j];
                f4 v = tab4[q >> 1];
                f2 lov = {v.x, v.y};
                f2 hiv = {v.z, v.w};
                bool hi = (q & 1u) != 0u;
                e[s][j]     = hi ? hiv : lov;   // entry q     (x = bx)
                e[s][j + 4] = hi ? lov : hiv;   // entry q ^ 1 (x = bx+1)
            }
        } else {
            #pragma unroll
            for (int c = 0; c < 8; ++c)
                e[s][c] = tab[idx[s][c]];
        }
    }

    #pragma unroll
    for (int s = 0; s < PTS_PER_THREAD; ++s) {
        float owx = 1.f - wx[s], owy = 1.f - wy[s], owz = 1.f - wz[s];

        f2 c00 = e[s][0] * owx + e[s][4] * wx[s];
        f2 c01 = e[s][1] * owx + e[s][5] * wx[s];
        f2 c10 = e[s][2] * owx + e[s][6] * wx[s];
        f2 c11 = e[s][3] * owx + e[s][7] * wx[s];

        f2 c0 = c00 * owy + c10 * wy[s];
        f2 c1 = c01 * owy + c11 * wy[s];

        f2 cv = c0 * owz + c1 * wz[s];

        if (valid[s]) {
            if constexpr (WRITE_TMP) {
                // Coalesced 8B/lane, single-writer line, cache-merged.
                tmp[(size_t)trow * n_points + pp[s]] = cv;
            } else {
                f2* dst = (f2*)(out + (size_t)pp[s] * 32) + level;
                *dst = cv;
            }
        }
    }
}

// No-LDS transpose: thread t owns point p. Reads tmp[l][p] for l in [0,NL)
// (each wave instruction = 64 lanes x 8B contiguous = coalesced 512B), then
// writes the point's NL*2 floats as NL/2 f4 PLAIN stores (128B contiguous per
// thread; the wave's NL/2 store instructions fully dirty each 64B line, L2
// write-merges -> no partial-line RMW). No LDS -> no occupancy cap, no sync.
template <int NL>
__global__ __launch_bounds__(256) void transpose_kernel(
    const f2* __restrict__ tmp,
    float* __restrict__ out,
    int n_points,
    int lb)
{
    int p = blockIdx.x * blockDim.x + threadIdx.x;
    int stride = gridDim.x * blockDim.x;
    f4* out4 = (f4*)out;

    for (; p < n_points; p += stride) {
        f2 v[NL];
        #pragma unroll
        for (int l = 0; l < NL; ++l)
            v[l] = tmp[(size_t)l * n_points + p];   // 16 independent loads

        #pragma unroll
        for (int k = 0; k < NL / 2; ++k) {
            f4 w = {v[2 * k].x, v[2 * k].y, v[2 * k + 1].x, v[2 * k + 1].y};
            out4[(size_t)p * 8 + lb / 2 + k] = w;   // plain store: L2 merges
        }
    }
}

extern "C" void kernel_launch(void* const* d_in, const int* in_sizes, int n_in,
                              void* d_out, int out_size, void* d_ws, size_t ws_size,
                              hipStream_t stream) {
    const float* x      = (const float*)d_in[0];
    const float* tables = (const float*)d_in[1];
    float* out = (float*)d_out;
    int n_points = in_sizes[0] / 3;
    float* mask_out = out + (size_t)n_points * 32;

    int chunks = (n_points + 256 * PTS_PER_THREAD - 1) / (256 * PTS_PER_THREAD);
    int blocks_per_phase = chunks * 8;
    int tblocks = (n_points + 255) / 256;
    if (tblocks > 4096) tblocks = 4096;   // grid-stride beyond this

    size_t need_full = (size_t)n_points * 16 * sizeof(f2);  // 128MB @ 1M pts
    size_t need_half = (size_t)n_points * 8 * sizeof(f2);   //  64MB

    if (n_points > 0 && ws_size >= need_full) {
        f2* tmp = (f2*)d_ws;
        hipLaunchKernelGGL((hash_encode_kernel<true>), dim3(blocks_per_phase * 2),
                           dim3(256), 0, stream,
                           x, tables, tmp, out, mask_out, n_points,
                           blocks_per_phase, 0, 1);
        hipLaunchKernelGGL((transpose_kernel<16>), dim3(tblocks), dim3(256), 0,
                           stream, tmp, out, n_points, 0);
    } else if (n_points > 0 && ws_size >= need_half) {
        f2* tmp = (f2*)d_ws;
        // Phase A: levels 0-7 -> tmp rows 0-7 -> out floats [0,16)
        hipLaunchKernelGGL((hash_encode_kernel<true>), dim3(blocks_per_phase),
                           dim3(256), 0, stream,
                           x, tables, tmp, out, mask_out, n_points,
                           blocks_per_phase, 0, 0);
        hipLaunchKernelGGL((transpose_kernel<8>), dim3(tblocks), dim3(256), 0,
                           stream, tmp, out, n_points, 0);
        // Phase B: levels 8-15 -> tmp rows 0-7 -> out floats [16,32)
        hipLaunchKernelGGL((hash_encode_kernel<true>), dim3(blocks_per_phase),
                           dim3(256), 0, stream,
                           x, tables, tmp, out, mask_out, n_points,
                           blocks_per_phase, 8, 0);
        hipLaunchKernelGGL((transpose_kernel<8>), dim3(tblocks), dim3(256), 0,
                           stream, tmp, out, n_points, 8);
    } else {
        hipLaunchKernelGGL((hash_encode_kernel<false>), dim3(blocks_per_phase * 2),
                           dim3(256), 0, stream,
                           x, tables, (f2*)nullptr, out, mask_out, n_points,
                           blocks_per_phase, 0, 1);
    }
}